// Round 1
// baseline (227.890 us; speedup 1.0000x reference)
//
#include <hip/hip_runtime.h>
#include <math.h>

#define NB 2
#define NO 512
#define NQ 512
#define LATENT 256
#define NHEADS 8
#define HEAD_DIM 32
#define HD 256
#define OUT_DIM 128

// ---------------------------------------------------------------------------
// Stable softplus: log1p(exp(x)) computed without overflow.
__device__ __forceinline__ float softplus_f(float x) {
  return x > 0.0f ? x + log1pf(expf(-x)) : log1pf(expf(x));
}

// ---------------------------------------------------------------------------
// Generic 1024x256x256 GEMM, 4 rows per block, 256 threads (one per out col).
// X rows are block-uniform -> scalar loads; W[k*256+n] coalesced across lanes.
template<int RELU>
__global__ __launch_bounds__(256) void mlp256_gemm(
    const float* __restrict__ X, const float* __restrict__ W,
    const float* __restrict__ bias, float* __restrict__ Y)
{
  const int n  = threadIdx.x;
  const int r0 = blockIdx.x * 4;
  float a0 = 0.f, a1 = 0.f, a2 = 0.f, a3 = 0.f;
  #pragma unroll 4
  for (int k = 0; k < 256; ++k) {
    float w = W[k * 256 + n];
    a0 = fmaf(X[(r0 + 0) * 256 + k], w, a0);
    a1 = fmaf(X[(r0 + 1) * 256 + k], w, a1);
    a2 = fmaf(X[(r0 + 2) * 256 + k], w, a2);
    a3 = fmaf(X[(r0 + 3) * 256 + k], w, a3);
  }
  float bb = bias[n];
  a0 += bb; a1 += bb; a2 += bb; a3 += bb;
  if (RELU) {
    a0 = fmaxf(a0, 0.f); a1 = fmaxf(a1, 0.f);
    a2 = fmaxf(a2, 0.f); a3 = fmaxf(a3, 0.f);
  }
  Y[(r0 + 0) * 256 + n] = a0;
  Y[(r0 + 1) * 256 + n] = a1;
  Y[(r0 + 2) * 256 + n] = a2;
  Y[(r0 + 3) * 256 + n] = a3;
}

// ---------------------------------------------------------------------------
// Aq[r][j] = kb1[j] + sum_i pos_query[r][i] * (kw1[i][j] + kw1[6+i][j])
// grid = B*NQ blocks, 256 threads.
__global__ __launch_bounds__(256) void make_aq(
    const float* __restrict__ pos_query, const float* __restrict__ kw1,
    const float* __restrict__ kb1, float* __restrict__ AQ)
{
  const int r = blockIdx.x;
  const int j = threadIdx.x;
  float p0 = pos_query[r * 3 + 0];
  float p1 = pos_query[r * 3 + 1];
  float p2 = pos_query[r * 3 + 2];
  float acc = kb1[j];
  acc = fmaf(p0, kw1[0 * 256 + j] + kw1[6 * 256 + j], acc);
  acc = fmaf(p1, kw1[1 * 256 + j] + kw1[7 * 256 + j], acc);
  acc = fmaf(p2, kw1[2 * 256 + j] + kw1[8 * 256 + j], acc);
  AQ[r * 256 + j] = acc;
}

// ---------------------------------------------------------------------------
// AOT[b][j][o] = sum_i pos_obs[b][o][i] * (kw1[3+i][j] - kw1[6+i][j])
// grid = B*256 blocks (one per (b,j)), 512 threads (one per o). Coalesced writes.
__global__ __launch_bounds__(512) void make_aot(
    const float* __restrict__ pos_obs, const float* __restrict__ kw1,
    float* __restrict__ AOT)
{
  const int b = blockIdx.x >> 8;
  const int j = blockIdx.x & 255;
  const int o = threadIdx.x;
  float w0 = kw1[3 * 256 + j] - kw1[6 * 256 + j];
  float w1 = kw1[4 * 256 + j] - kw1[7 * 256 + j];
  float w2 = kw1[5 * 256 + j] - kw1[8 * 256 + j];
  const float* p = pos_obs + ((size_t)b * NO + o) * 3;
  AOT[((size_t)b * 256 + j) * NO + o] = fmaf(p[0], w0, fmaf(p[1], w1, p[2] * w2));
}

// ---------------------------------------------------------------------------
// The big fused attention kernel. One workgroup per (b,q), 256 threads.
// Phase 1: each thread owns obs pair (2t, 2t+1); 256-j loop accumulates the
//          per-head delta via relu(aq_j + ao_j) * kw2[j][h]; logits -> LDS.
// Phase 2: per-head softmax (one wave per 2 heads), unnormalized p back to LDS.
// Phase 3: thread t = (h,d) accumulates s1 = sum p*v, s2 = sum p*v^2 over o.
//          mean = s1/S ; var = s2/S - mean^2.
__global__ __launch_bounds__(256, 4) void attn_fused(
    const float* __restrict__ AQ,        // (B*NQ, 256)
    const float* __restrict__ AOT,       // (B, 256, NO)
    const float* __restrict__ V,         // (B*NO, 256) layout [b][o][h*32+d]
    const float* __restrict__ kw2,       // (256, 8)
    const float* __restrict__ kb2,       // (8)
    const float* __restrict__ log_sigma, // (8)
    const float* __restrict__ pos_obs,   // (B*NO, 3)
    const float* __restrict__ pos_query, // (B*NQ, 3)
    float* __restrict__ HQ,              // (B*NQ, 256)
    float* __restrict__ VAR)             // (B*NQ, 256)
{
  __shared__ float s_aq[256];
  __shared__ float s_kw2[256 * 8];
  __shared__ float s_logits[8 * 512];   // 16 KB
  __shared__ float s_invs2[8];
  __shared__ float s_kb2[8];
  __shared__ float s_pq[3];
  __shared__ float s_sum[8];

  const int t  = threadIdx.x;
  const int bq = blockIdx.x;            // b*NQ + q
  const int b  = bq >> 9;

  s_aq[t] = AQ[bq * 256 + t];
  #pragma unroll
  for (int i = t; i < 2048; i += 256) s_kw2[i] = kw2[i];
  if (t < 8) {
    float s = expf(log_sigma[t]);
    s_invs2[t] = 1.0f / (s * s + 1e-6f);
    s_kb2[t]   = kb2[t];
  }
  if (t < 3) s_pq[t] = pos_query[bq * 3 + t];
  __syncthreads();

  // squared distances for this thread's obs pair
  const int o0 = 2 * t, o1 = 2 * t + 1;
  const float pq0 = s_pq[0], pq1 = s_pq[1], pq2 = s_pq[2];
  const float* po = pos_obs + (size_t)b * NO * 3;
  float d2a, d2b;
  {
    float r0 = pq0 - po[o0 * 3 + 0];
    float r1 = pq1 - po[o0 * 3 + 1];
    float r2 = pq2 - po[o0 * 3 + 2];
    d2a = r0 * r0 + r1 * r1 + r2 * r2;
  }
  {
    float r0 = pq0 - po[o1 * 3 + 0];
    float r1 = pq1 - po[o1 * 3 + 1];
    float r2 = pq2 - po[o1 * 3 + 2];
    d2b = r0 * r0 + r1 * r1 + r2 * r2;
  }

  // Phase 1: per-head delta accumulation
  float da[8] = {0.f, 0.f, 0.f, 0.f, 0.f, 0.f, 0.f, 0.f};
  float db[8] = {0.f, 0.f, 0.f, 0.f, 0.f, 0.f, 0.f, 0.f};
  const float2* aot = (const float2*)(AOT + (size_t)b * 256 * NO);
  #pragma unroll 4
  for (int j = 0; j < 256; ++j) {
    float aq = s_aq[j];
    float2 ao = aot[j * 256 + t];       // coalesced, L2-resident
    float h0 = fmaxf(aq + ao.x, 0.f);
    float h1 = fmaxf(aq + ao.y, 0.f);
    const float4* kwp = (const float4*)(s_kw2 + j * 8);
    float4 k0 = kwp[0], k1 = kwp[1];
    da[0] = fmaf(h0, k0.x, da[0]); db[0] = fmaf(h1, k0.x, db[0]);
    da[1] = fmaf(h0, k0.y, da[1]); db[1] = fmaf(h1, k0.y, db[1]);
    da[2] = fmaf(h0, k0.z, da[2]); db[2] = fmaf(h1, k0.z, db[2]);
    da[3] = fmaf(h0, k0.w, da[3]); db[3] = fmaf(h1, k0.w, db[3]);
    da[4] = fmaf(h0, k1.x, da[4]); db[4] = fmaf(h1, k1.x, db[4]);
    da[5] = fmaf(h0, k1.y, da[5]); db[5] = fmaf(h1, k1.y, db[5]);
    da[6] = fmaf(h0, k1.z, da[6]); db[6] = fmaf(h1, k1.z, db[6]);
    da[7] = fmaf(h0, k1.w, da[7]); db[7] = fmaf(h1, k1.w, db[7]);
  }
  #pragma unroll
  for (int h = 0; h < 8; ++h) {
    float inv = s_invs2[h];
    float l0 = logf(expf(-d2a * inv) + 1e-8f) + da[h] + s_kb2[h];
    float l1 = logf(expf(-d2b * inv) + 1e-8f) + db[h] + s_kb2[h];
    s_logits[h * 512 + o0] = l0;
    s_logits[h * 512 + o1] = l1;
  }
  __syncthreads();

  // Phase 2: per-head softmax (wave w handles heads w, w+4)
  const int wave = t >> 6, lane = t & 63;
  for (int h = wave; h < 8; h += 4) {
    float l[8];
    float m = -1e30f;
    #pragma unroll
    for (int k = 0; k < 8; ++k) {
      l[k] = s_logits[h * 512 + k * 64 + lane];
      m = fmaxf(m, l[k]);
    }
    #pragma unroll
    for (int off = 32; off >= 1; off >>= 1) m = fmaxf(m, __shfl_xor(m, off, 64));
    float s = 0.f;
    #pragma unroll
    for (int k = 0; k < 8; ++k) {
      float p = expf(l[k] - m);
      s_logits[h * 512 + k * 64 + lane] = p;
      s += p;
    }
    #pragma unroll
    for (int off = 32; off >= 1; off >>= 1) s += __shfl_xor(s, off, 64);
    if (lane == 0) s_sum[h] = s;
  }
  __syncthreads();

  // Phase 3: weighted mean and variance. t = h*32 + d matches V's hd index.
  const int h = t >> 5;
  const float* vb_ = V + (size_t)b * NO * 256;
  const float* pl  = s_logits + h * 512;
  float s1 = 0.f, s2 = 0.f;
  #pragma unroll 4
  for (int o = 0; o < 512; ++o) {
    float p  = pl[o];
    float vv = vb_[o * 256 + t];        // coalesced, L2-resident
    s1 = fmaf(p, vv, s1);
    s2 = fmaf(p * vv, vv, s2);
  }
  float inv = 1.0f / s_sum[h];
  float m1 = s1 * inv;
  float va = fmaxf(s2 * inv - m1 * m1, 0.f);
  HQ[bq * 256 + t]  = m1;
  VAR[bq * 256 + t] = va;
}

// ---------------------------------------------------------------------------
// Output projections: mean = HQ @ ow + ob ; var_out = softplus(VAR @ vw + vb)
// grid.x = 256 (4 rows/block), grid.y = 2 (mode), 128 threads (one per col).
__global__ __launch_bounds__(128) void out_proj(
    const float* __restrict__ HQ, const float* __restrict__ ow,
    const float* __restrict__ ob, const float* __restrict__ VAR,
    const float* __restrict__ vw, const float* __restrict__ vb,
    float* __restrict__ out)
{
  const int n    = threadIdx.x;
  const int r0   = blockIdx.x * 4;
  const int mode = blockIdx.y;
  const float* X    = mode ? VAR : HQ;
  const float* W    = mode ? vw : ow;
  const float* bias = mode ? vb : ob;
  float* Y = out + (size_t)mode * (NB * NQ * OUT_DIM);
  float a0 = 0.f, a1 = 0.f, a2 = 0.f, a3 = 0.f;
  #pragma unroll 4
  for (int k = 0; k < 256; ++k) {
    float w = W[k * 128 + n];
    a0 = fmaf(X[(r0 + 0) * 256 + k], w, a0);
    a1 = fmaf(X[(r0 + 1) * 256 + k], w, a1);
    a2 = fmaf(X[(r0 + 2) * 256 + k], w, a2);
    a3 = fmaf(X[(r0 + 3) * 256 + k], w, a3);
  }
  float bb = bias[n];
  a0 += bb; a1 += bb; a2 += bb; a3 += bb;
  if (mode) {
    a0 = softplus_f(a0); a1 = softplus_f(a1);
    a2 = softplus_f(a2); a3 = softplus_f(a3);
  }
  Y[(r0 + 0) * 128 + n] = a0;
  Y[(r0 + 1) * 128 + n] = a1;
  Y[(r0 + 2) * 128 + n] = a2;
  Y[(r0 + 3) * 128 + n] = a3;
}

// ---------------------------------------------------------------------------
extern "C" void kernel_launch(void* const* d_in, const int* in_sizes, int n_in,
                              void* d_out, int out_size, void* d_ws, size_t ws_size,
                              hipStream_t stream)
{
  const float* h_obs     = (const float*)d_in[0];
  const float* pos_obs   = (const float*)d_in[1];
  const float* pos_query = (const float*)d_in[2];
  const float* fw1       = (const float*)d_in[3];
  const float* fb1       = (const float*)d_in[4];
  const float* fw2       = (const float*)d_in[5];
  const float* fb2       = (const float*)d_in[6];
  const float* log_sigma = (const float*)d_in[7];
  const float* kw1       = (const float*)d_in[8];
  const float* kb1       = (const float*)d_in[9];
  const float* kw2       = (const float*)d_in[10];
  const float* kb2       = (const float*)d_in[11];
  const float* ow        = (const float*)d_in[12];
  const float* ob        = (const float*)d_in[13];
  const float* vw        = (const float*)d_in[14];
  const float* vb        = (const float*)d_in[15];

  float* out = (float*)d_out;
  float* ws  = (float*)d_ws;

  // workspace layout (floats); X1 dead after layer-2 GEMM, reused for HQ
  float* X1  = ws;                 // 262144 (B*NO x 256)
  float* V   = ws + 262144;        // 262144
  float* AQ  = ws + 524288;        // 262144
  float* AOT = ws + 786432;        // 262144 (B x 256 x NO)
  float* VAR = ws + 1048576;       // 262144
  float* HQ  = X1;

  mlp256_gemm<1><<<256, 256, 0, stream>>>(h_obs, fw1, fb1, X1);
  mlp256_gemm<0><<<256, 256, 0, stream>>>(X1, fw2, fb2, V);
  make_aq<<<NB * NQ, 256, 0, stream>>>(pos_query, kw1, kb1, AQ);
  make_aot<<<NB * 256, 512, 0, stream>>>(pos_obs, kw1, AOT);
  attn_fused<<<NB * NQ, 256, 0, stream>>>(AQ, AOT, V, kw2, kb2, log_sigma,
                                          pos_obs, pos_query, HQ, VAR);
  out_proj<<<dim3(256, 2), 128, 0, stream>>>(HQ, ow, ob, VAR, vw, vb, out);
}

// Round 2
// 199.610 us; speedup vs baseline: 1.1417x; 1.1417x over previous
//
#include <hip/hip_runtime.h>
#include <math.h>

#define NB 2
#define NO 512
#define NQ 512
#define LATENT 256
#define NHEADS 8
#define HEAD_DIM 32
#define HD 256
#define OUT_DIM 128

// ---------------------------------------------------------------------------
__device__ __forceinline__ float softplus_f(float x) {
  return x > 0.0f ? x + log1pf(expf(-x)) : log1pf(expf(x));
}

// ---------------------------------------------------------------------------
// K-split GEMM: Y(1024x256) = act(X(1024x256) @ W(256x256) + b)
// 256 blocks, 1024 threads = 256 cols x 4 K-slices. 16 waves/CU.
template<int RELU>
__global__ __launch_bounds__(1024) void mlp256_ksplit(
    const float* __restrict__ X, const float* __restrict__ W,
    const float* __restrict__ bias, float* __restrict__ Y)
{
  __shared__ float s_red[4][4][256];
  const int n  = threadIdx.x & 255;
  const int ks = threadIdx.x >> 8;      // 0..3
  const int r0 = blockIdx.x * 4;
  float a0 = 0.f, a1 = 0.f, a2 = 0.f, a3 = 0.f;
  const int k0 = ks * 64;
  #pragma unroll 8
  for (int kk = 0; kk < 64; ++kk) {
    int k = k0 + kk;
    float w = W[k * 256 + n];
    a0 = fmaf(X[(r0 + 0) * 256 + k], w, a0);
    a1 = fmaf(X[(r0 + 1) * 256 + k], w, a1);
    a2 = fmaf(X[(r0 + 2) * 256 + k], w, a2);
    a3 = fmaf(X[(r0 + 3) * 256 + k], w, a3);
  }
  s_red[ks][0][n] = a0; s_red[ks][1][n] = a1;
  s_red[ks][2][n] = a2; s_red[ks][3][n] = a3;
  __syncthreads();
  if (ks == 0) {
    float bb = bias[n];
    #pragma unroll
    for (int i = 0; i < 4; ++i) {
      float v = s_red[0][i][n] + s_red[1][i][n] + s_red[2][i][n] + s_red[3][i][n] + bb;
      if (RELU) v = fmaxf(v, 0.f);
      Y[(r0 + i) * 256 + n] = v;
    }
  }
}

// ---------------------------------------------------------------------------
// AOT[b][j][o] = sum_i pos_obs[b][o][i] * (kw1[3+i][j] - kw1[6+i][j])
__global__ __launch_bounds__(512) void make_aot(
    const float* __restrict__ pos_obs, const float* __restrict__ kw1,
    float* __restrict__ AOT)
{
  const int b = blockIdx.x >> 8;
  const int j = blockIdx.x & 255;
  const int o = threadIdx.x;
  float w0 = kw1[3 * 256 + j] - kw1[6 * 256 + j];
  float w1 = kw1[4 * 256 + j] - kw1[7 * 256 + j];
  float w2 = kw1[5 * 256 + j] - kw1[8 * 256 + j];
  const float* p = pos_obs + ((size_t)b * NO + o) * 3;
  AOT[((size_t)b * 256 + j) * NO + o] = fmaf(p[0], w0, fmaf(p[1], w1, p[2] * w2));
}

// ---------------------------------------------------------------------------
// Fused attention: one workgroup per (b,q), 256 threads. Aq computed inline.
__global__ __launch_bounds__(256, 4) void attn_fused(
    const float* __restrict__ AOT,       // (B, 256, NO)
    const float* __restrict__ V,         // (B*NO, 256)
    const float* __restrict__ kw1,       // (9, 256)
    const float* __restrict__ kb1,       // (256)
    const float* __restrict__ kw2,       // (256, 8)
    const float* __restrict__ kb2,       // (8)
    const float* __restrict__ log_sigma, // (8)
    const float* __restrict__ pos_obs,   // (B*NO, 3)
    const float* __restrict__ pos_query, // (B*NQ, 3)
    float* __restrict__ HQ,              // (B*NQ, 256)
    float* __restrict__ VAR)             // (B*NQ, 256)
{
  __shared__ float s_aq[256];
  __shared__ float s_kw2[256 * 8];
  __shared__ float s_logits[8 * 512];   // 16 KB
  __shared__ float s_invs2[8];
  __shared__ float s_kb2[8];
  __shared__ float s_sum[8];

  const int t  = threadIdx.x;
  const int bq = blockIdx.x;            // b*NQ + q
  const int b  = bq >> 9;

  // pos_query address is block-uniform -> scalar loads
  const float pq0 = pos_query[bq * 3 + 0];
  const float pq1 = pos_query[bq * 3 + 1];
  const float pq2 = pos_query[bq * 3 + 2];

  // fused make_aq: aq[t] = kb1[t] + sum_i pq_i * (kw1[i][t] + kw1[6+i][t])
  {
    float acc = kb1[t];
    acc = fmaf(pq0, kw1[0 * 256 + t] + kw1[6 * 256 + t], acc);
    acc = fmaf(pq1, kw1[1 * 256 + t] + kw1[7 * 256 + t], acc);
    acc = fmaf(pq2, kw1[2 * 256 + t] + kw1[8 * 256 + t], acc);
    s_aq[t] = acc;
  }
  #pragma unroll
  for (int i = t; i < 2048; i += 256) s_kw2[i] = kw2[i];
  if (t < 8) {
    float s = expf(log_sigma[t]);
    s_invs2[t] = 1.0f / (s * s + 1e-6f);
    s_kb2[t]   = kb2[t];
  }
  __syncthreads();

  // squared distances for this thread's obs pair
  const int o0 = 2 * t, o1 = 2 * t + 1;
  const float* po = pos_obs + (size_t)b * NO * 3;
  float d2a, d2b;
  {
    float r0 = pq0 - po[o0 * 3 + 0];
    float r1 = pq1 - po[o0 * 3 + 1];
    float r2 = pq2 - po[o0 * 3 + 2];
    d2a = r0 * r0 + r1 * r1 + r2 * r2;
  }
  {
    float r0 = pq0 - po[o1 * 3 + 0];
    float r1 = pq1 - po[o1 * 3 + 1];
    float r2 = pq2 - po[o1 * 3 + 2];
    d2b = r0 * r0 + r1 * r1 + r2 * r2;
  }

  // Phase 1: per-head delta accumulation over j = 0..255
  float da[8] = {0.f, 0.f, 0.f, 0.f, 0.f, 0.f, 0.f, 0.f};
  float db[8] = {0.f, 0.f, 0.f, 0.f, 0.f, 0.f, 0.f, 0.f};
  const float2* aot = (const float2*)(AOT + (size_t)b * 256 * NO);
  #pragma unroll 4
  for (int j = 0; j < 256; ++j) {
    float aq = s_aq[j];
    float2 ao = aot[j * 256 + t];       // coalesced, L2-resident
    float h0 = fmaxf(aq + ao.x, 0.f);
    float h1 = fmaxf(aq + ao.y, 0.f);
    const float4* kwp = (const float4*)(s_kw2 + j * 8);
    float4 k0 = kwp[0], k1 = kwp[1];
    da[0] = fmaf(h0, k0.x, da[0]); db[0] = fmaf(h1, k0.x, db[0]);
    da[1] = fmaf(h0, k0.y, da[1]); db[1] = fmaf(h1, k0.y, db[1]);
    da[2] = fmaf(h0, k0.z, da[2]); db[2] = fmaf(h1, k0.z, db[2]);
    da[3] = fmaf(h0, k0.w, da[3]); db[3] = fmaf(h1, k0.w, db[3]);
    da[4] = fmaf(h0, k1.x, da[4]); db[4] = fmaf(h1, k1.x, db[4]);
    da[5] = fmaf(h0, k1.y, da[5]); db[5] = fmaf(h1, k1.y, db[5]);
    da[6] = fmaf(h0, k1.z, da[6]); db[6] = fmaf(h1, k1.z, db[6]);
    da[7] = fmaf(h0, k1.w, da[7]); db[7] = fmaf(h1, k1.w, db[7]);
  }
  #pragma unroll
  for (int h = 0; h < 8; ++h) {
    float inv = s_invs2[h];
    float l0 = logf(expf(-d2a * inv) + 1e-8f) + da[h] + s_kb2[h];
    float l1 = logf(expf(-d2b * inv) + 1e-8f) + db[h] + s_kb2[h];
    s_logits[h * 512 + o0] = l0;
    s_logits[h * 512 + o1] = l1;
  }
  __syncthreads();

  // Phase 2: per-head softmax (wave w handles heads w, w+4)
  const int wave = t >> 6, lane = t & 63;
  for (int h = wave; h < 8; h += 4) {
    float l[8];
    float m = -1e30f;
    #pragma unroll
    for (int k = 0; k < 8; ++k) {
      l[k] = s_logits[h * 512 + k * 64 + lane];
      m = fmaxf(m, l[k]);
    }
    #pragma unroll
    for (int off = 32; off >= 1; off >>= 1) m = fmaxf(m, __shfl_xor(m, off, 64));
    float s = 0.f;
    #pragma unroll
    for (int k = 0; k < 8; ++k) {
      float p = expf(l[k] - m);
      s_logits[h * 512 + k * 64 + lane] = p;
      s += p;
    }
    #pragma unroll
    for (int off = 32; off >= 1; off >>= 1) s += __shfl_xor(s, off, 64);
    if (lane == 0) s_sum[h] = s;
  }
  __syncthreads();

  // Phase 3: weighted mean and variance. t = h*32 + d matches V's hd index.
  const int h = t >> 5;
  const float* vb_ = V + (size_t)b * NO * 256;
  const float* pl  = s_logits + h * 512;
  float s1 = 0.f, s2 = 0.f;
  #pragma unroll 4
  for (int o = 0; o < 512; ++o) {
    float p  = pl[o];
    float vv = vb_[o * 256 + t];        // coalesced, L2-resident
    s1 = fmaf(p, vv, s1);
    s2 = fmaf(p * vv, vv, s2);
  }
  float inv = 1.0f / s_sum[h];
  float m1 = s1 * inv;
  float va = fmaxf(s2 * inv - m1 * m1, 0.f);
  HQ[bq * 256 + t]  = m1;
  VAR[bq * 256 + t] = va;
}

// ---------------------------------------------------------------------------
// Output projections, K-split: 1024 threads = 128 cols x 8 K-slices.
// grid (256, 2): 4 rows/block, mode 0 = mean, mode 1 = softplus(var proj).
__global__ __launch_bounds__(1024) void out_proj_ksplit(
    const float* __restrict__ HQ, const float* __restrict__ ow,
    const float* __restrict__ ob, const float* __restrict__ VAR,
    const float* __restrict__ vw, const float* __restrict__ vb,
    float* __restrict__ out)
{
  __shared__ float s_red[8][4][128];
  const int n    = threadIdx.x & 127;
  const int ks   = threadIdx.x >> 7;    // 0..7
  const int r0   = blockIdx.x * 4;
  const int mode = blockIdx.y;
  const float* X    = mode ? VAR : HQ;
  const float* W    = mode ? vw : ow;
  const float* bias = mode ? vb : ob;
  float* Y = out + (size_t)mode * (NB * NQ * OUT_DIM);
  float a0 = 0.f, a1 = 0.f, a2 = 0.f, a3 = 0.f;
  const int k0 = ks * 32;
  #pragma unroll 8
  for (int kk = 0; kk < 32; ++kk) {
    int k = k0 + kk;
    float w = W[k * 128 + n];
    a0 = fmaf(X[(r0 + 0) * 256 + k], w, a0);
    a1 = fmaf(X[(r0 + 1) * 256 + k], w, a1);
    a2 = fmaf(X[(r0 + 2) * 256 + k], w, a2);
    a3 = fmaf(X[(r0 + 3) * 256 + k], w, a3);
  }
  s_red[ks][0][n] = a0; s_red[ks][1][n] = a1;
  s_red[ks][2][n] = a2; s_red[ks][3][n] = a3;
  __syncthreads();
  if (ks == 0) {
    float bb = bias[n];
    #pragma unroll
    for (int i = 0; i < 4; ++i) {
      float v = bb;
      #pragma unroll
      for (int s = 0; s < 8; ++s) v += s_red[s][i][n];
      if (mode) v = softplus_f(v);
      Y[(r0 + i) * 128 + n] = v;
    }
  }
}

// ---------------------------------------------------------------------------
extern "C" void kernel_launch(void* const* d_in, const int* in_sizes, int n_in,
                              void* d_out, int out_size, void* d_ws, size_t ws_size,
                              hipStream_t stream)
{
  const float* h_obs     = (const float*)d_in[0];
  const float* pos_obs   = (const float*)d_in[1];
  const float* pos_query = (const float*)d_in[2];
  const float* fw1       = (const float*)d_in[3];
  const float* fb1       = (const float*)d_in[4];
  const float* fw2       = (const float*)d_in[5];
  const float* fb2       = (const float*)d_in[6];
  const float* log_sigma = (const float*)d_in[7];
  const float* kw1       = (const float*)d_in[8];
  const float* kb1       = (const float*)d_in[9];
  const float* kw2       = (const float*)d_in[10];
  const float* kb2       = (const float*)d_in[11];
  const float* ow        = (const float*)d_in[12];
  const float* ob        = (const float*)d_in[13];
  const float* vw        = (const float*)d_in[14];
  const float* vb        = (const float*)d_in[15];

  float* out = (float*)d_out;
  float* ws  = (float*)d_ws;

  // workspace layout (floats); X1 dead after layer-2 GEMM, reused for HQ
  float* X1  = ws;                 // 262144 (B*NO x 256)
  float* V   = ws + 262144;        // 262144
  float* AOT = ws + 524288;        // 262144 (B x 256 x NO)
  float* VAR = ws + 786432;        // 262144
  float* HQ  = X1;

  mlp256_ksplit<1><<<256, 1024, 0, stream>>>(h_obs, fw1, fb1, X1);
  mlp256_ksplit<0><<<256, 1024, 0, stream>>>(X1, fw2, fb2, V);
  make_aot<<<NB * 256, 512, 0, stream>>>(pos_obs, kw1, AOT);
  attn_fused<<<NB * NQ, 256, 0, stream>>>(AOT, V, kw1, kb1, kw2, kb2, log_sigma,
                                          pos_obs, pos_query, HQ, VAR);
  out_proj_ksplit<<<dim3(256, 2), 1024, 0, stream>>>(HQ, ow, ob, VAR, vw, vb, out);
}

// Round 3
// 185.332 us; speedup vs baseline: 1.2296x; 1.0770x over previous
//
#include <hip/hip_runtime.h>
#include <math.h>

#define NB 2
#define NO 512
#define NQ 512
#define LATENT 256
#define NHEADS 8
#define HEAD_DIM 32
#define HD 256
#define OUT_DIM 128

// ---------------------------------------------------------------------------
__device__ __forceinline__ float softplus_f(float x) {
  return x > 0.0f ? x + log1pf(expf(-x)) : log1pf(expf(x));
}

// ---------------------------------------------------------------------------
// K-split GEMM: Y(1024x256) = act(X(1024x256) @ W(256x256) + b)
// 256 blocks, 1024 threads = 256 cols x 4 K-slices. 16 waves/CU.
template<int RELU>
__global__ __launch_bounds__(1024) void mlp256_ksplit(
    const float* __restrict__ X, const float* __restrict__ W,
    const float* __restrict__ bias, float* __restrict__ Y)
{
  __shared__ float s_red[4][4][256];
  const int n  = threadIdx.x & 255;
  const int ks = threadIdx.x >> 8;      // 0..3
  const int r0 = blockIdx.x * 4;
  float a0 = 0.f, a1 = 0.f, a2 = 0.f, a3 = 0.f;
  const int k0 = ks * 64;
  #pragma unroll 8
  for (int kk = 0; kk < 64; ++kk) {
    int k = k0 + kk;
    float w = W[k * 256 + n];
    a0 = fmaf(X[(r0 + 0) * 256 + k], w, a0);
    a1 = fmaf(X[(r0 + 1) * 256 + k], w, a1);
    a2 = fmaf(X[(r0 + 2) * 256 + k], w, a2);
    a3 = fmaf(X[(r0 + 3) * 256 + k], w, a3);
  }
  s_red[ks][0][n] = a0; s_red[ks][1][n] = a1;
  s_red[ks][2][n] = a2; s_red[ks][3][n] = a3;
  __syncthreads();
  if (ks == 0) {
    float bb = bias[n];
    #pragma unroll
    for (int i = 0; i < 4; ++i) {
      float v = s_red[0][i][n] + s_red[1][i][n] + s_red[2][i][n] + s_red[3][i][n] + bb;
      if (RELU) v = fmaxf(v, 0.f);
      Y[(r0 + i) * 256 + n] = v;
    }
  }
}

// ---------------------------------------------------------------------------
// Fused attention, QT=2 queries per block, 512 threads (8 waves).
// sub = t>>8 selects the query; tt = t&255 is the obs-pair / output index.
// Phase 1: per-thread j-loop; ao recomputed inline from pos_obs (regs) and
//          kw1 combos (scalar loads, wave-uniform j); kw2 via s_load_dwordx8.
// Phase 2: per-(sub,h) softmax, one wave handles 2 heads.
// Phase 3: thread = (sub, o-quarter, h, d4): float4 V loads, p from padded
//          LDS (conflict-free), 4-way o-split reduced through LDS.
__global__ __launch_bounds__(512, 2) void attn_fused(
    const float* __restrict__ V,         // (B*NO, 256)
    const float* __restrict__ kw1,       // (9, 256)
    const float* __restrict__ kb1,       // (256)
    const float* __restrict__ kw2,       // (256, 8)
    const float* __restrict__ kb2,       // (8)
    const float* __restrict__ log_sigma, // (8)
    const float* __restrict__ pos_obs,   // (B*NO, 3)
    const float* __restrict__ pos_query, // (B*NQ, 3)
    float* __restrict__ HQ,              // (B*NQ, 256)
    float* __restrict__ VAR)             // (B*NQ, 256)
{
  __shared__ float s_aq[2][256];
  __shared__ float s_logits[2][8 * 513];   // +1-row pad: phase-3 bank spread
  __shared__ float s_red[512][8];
  __shared__ float s_sum[2][8];
  __shared__ float s_invs2[8];
  __shared__ float s_kb2v[8];

  const int t   = threadIdx.x;
  const int sub = t >> 8;                  // wave-uniform (waves 0-3 / 4-7)
  const int tt  = t & 255;
  const int bq0 = blockIdx.x * 2;
  const int b   = bq0 >> 9;
  const int bq  = bq0 + sub;

  const float pq0 = pos_query[bq * 3 + 0];
  const float pq1 = pos_query[bq * 3 + 1];
  const float pq2 = pos_query[bq * 3 + 2];

  // aq[sub][j] = kb1[j] + sum_i pq_i * (kw1[i][j] + kw1[6+i][j])
  {
    const int j = tt;
    float acc = kb1[j];
    acc = fmaf(pq0, kw1[0 * 256 + j] + kw1[6 * 256 + j], acc);
    acc = fmaf(pq1, kw1[1 * 256 + j] + kw1[7 * 256 + j], acc);
    acc = fmaf(pq2, kw1[2 * 256 + j] + kw1[8 * 256 + j], acc);
    s_aq[sub][j] = acc;
  }
  if (t < 8) {
    float s = expf(log_sigma[t]);
    s_invs2[t] = 1.0f / (s * s + 1e-6f);
    s_kb2v[t]  = kb2[t];
  }
  __syncthreads();

  // this thread's obs pair: positions held in registers for the whole kernel
  const int o0 = 2 * tt, o1 = o0 + 1;
  const float* po = pos_obs + (size_t)b * NO * 3;
  const float p0x = po[o0 * 3 + 0], p0y = po[o0 * 3 + 1], p0z = po[o0 * 3 + 2];
  const float p1x = po[o1 * 3 + 0], p1y = po[o1 * 3 + 1], p1z = po[o1 * 3 + 2];
  float d2a, d2b;
  {
    float r0 = pq0 - p0x, r1 = pq1 - p0y, r2 = pq2 - p0z;
    d2a = r0 * r0 + r1 * r1 + r2 * r2;
  }
  {
    float r0 = pq0 - p1x, r1 = pq1 - p1y, r2 = pq2 - p1z;
    d2b = r0 * r0 + r1 * r1 + r2 * r2;
  }

  // Phase 1: delta accumulation; ao computed inline (no AOT array at all)
  const float* k3 = kw1 + 3 * 256;
  const float* k4 = kw1 + 4 * 256;
  const float* k5 = kw1 + 5 * 256;
  const float* k6 = kw1 + 6 * 256;
  const float* k7 = kw1 + 7 * 256;
  const float* k8 = kw1 + 8 * 256;
  float da[8] = {0.f, 0.f, 0.f, 0.f, 0.f, 0.f, 0.f, 0.f};
  float db[8] = {0.f, 0.f, 0.f, 0.f, 0.f, 0.f, 0.f, 0.f};
  #pragma unroll 4
  for (int j = 0; j < 256; ++j) {
    float w0 = k3[j] - k6[j];            // wave-uniform j -> s_load + VALU
    float w1 = k4[j] - k7[j];
    float w2 = k5[j] - k8[j];
    float aqv = s_aq[sub][j];            // LDS broadcast (1 b32 per j)
    float ao0 = fmaf(p0x, w0, fmaf(p0y, w1, p0z * w2));
    float ao1 = fmaf(p1x, w0, fmaf(p1y, w1, p1z * w2));
    float h0 = fmaxf(aqv + ao0, 0.f);
    float h1 = fmaxf(aqv + ao1, 0.f);
    const float* kr = kw2 + j * 8;       // wave-uniform -> s_load_dwordx8
    da[0] = fmaf(h0, kr[0], da[0]); db[0] = fmaf(h1, kr[0], db[0]);
    da[1] = fmaf(h0, kr[1], da[1]); db[1] = fmaf(h1, kr[1], db[1]);
    da[2] = fmaf(h0, kr[2], da[2]); db[2] = fmaf(h1, kr[2], db[2]);
    da[3] = fmaf(h0, kr[3], da[3]); db[3] = fmaf(h1, kr[3], db[3]);
    da[4] = fmaf(h0, kr[4], da[4]); db[4] = fmaf(h1, kr[4], db[4]);
    da[5] = fmaf(h0, kr[5], da[5]); db[5] = fmaf(h1, kr[5], db[5]);
    da[6] = fmaf(h0, kr[6], da[6]); db[6] = fmaf(h1, kr[6], db[6]);
    da[7] = fmaf(h0, kr[7], da[7]); db[7] = fmaf(h1, kr[7], db[7]);
  }
  #pragma unroll
  for (int h = 0; h < 8; ++h) {
    float inv = s_invs2[h];
    float l0 = logf(expf(-d2a * inv) + 1e-8f) + da[h] + s_kb2v[h];
    float l1 = logf(expf(-d2b * inv) + 1e-8f) + db[h] + s_kb2v[h];
    s_logits[sub][h * 513 + o0] = l0;
    s_logits[sub][h * 513 + o1] = l1;
  }
  __syncthreads();

  // Phase 2: softmax. 8 waves x 2 heads = 16 (sub,h) combos.
  {
    const int wave = t >> 6, lane = t & 63;
    const int sw = wave >> 2;
    #pragma unroll
    for (int hh = 0; hh < 2; ++hh) {
      const int h = (wave & 3) + hh * 4;
      float* pl = &s_logits[sw][h * 513];
      float l[8];
      float m = -1e30f;
      #pragma unroll
      for (int k = 0; k < 8; ++k) {
        l[k] = pl[k * 64 + lane];
        m = fmaxf(m, l[k]);
      }
      #pragma unroll
      for (int off = 32; off >= 1; off >>= 1) m = fmaxf(m, __shfl_xor(m, off, 64));
      float s = 0.f;
      #pragma unroll
      for (int k = 0; k < 8; ++k) {
        float p = expf(l[k] - m);
        pl[k * 64 + lane] = p;
        s += p;
      }
      #pragma unroll
      for (int off = 32; off >= 1; off >>= 1) s += __shfl_xor(s, off, 64);
      if (lane == 0) s_sum[sw][h] = s;
    }
  }
  __syncthreads();

  // Phase 3: thread = (sub, q4 = o-quarter, h, d4-block of 4 d's)
  {
    const int q4 = tt >> 6;
    const int hd = tt & 63;
    const int h3 = hd >> 3;
    const int d4 = (hd & 7) * 4;
    const float* vbase = V + (size_t)b * NO * 256 + h3 * 32 + d4;
    const float* pl = &s_logits[sub][h3 * 513];
    float s1x = 0.f, s1y = 0.f, s1z = 0.f, s1w = 0.f;
    float s2x = 0.f, s2y = 0.f, s2z = 0.f, s2w = 0.f;
    const int ob = q4 * 128;
    #pragma unroll 4
    for (int oi = 0; oi < 128; ++oi) {
      int o = ob + oi;
      float p = pl[o];                            // padded -> conflict-free
      float4 vv = *(const float4*)(vbase + (size_t)o * 256);
      s1x = fmaf(p, vv.x, s1x); s2x = fmaf(p * vv.x, vv.x, s2x);
      s1y = fmaf(p, vv.y, s1y); s2y = fmaf(p * vv.y, vv.y, s2y);
      s1z = fmaf(p, vv.z, s1z); s2z = fmaf(p * vv.z, vv.z, s2z);
      s1w = fmaf(p, vv.w, s1w); s2w = fmaf(p * vv.w, vv.w, s2w);
    }
    float4 r1 = {s1x, s1y, s1z, s1w};
    float4 r2 = {s2x, s2y, s2z, s2w};
    *(float4*)&s_red[t][0] = r1;
    *(float4*)&s_red[t][4] = r2;
  }
  __syncthreads();

  // Reduce over the 4 o-quarters and write outputs
  {
    const int sub2 = t >> 8;
    const int hd2  = t & 255;
    const int h2   = hd2 >> 5;
    const int d    = hd2 & 31;
    const int srcb = sub2 * 256 + h2 * 8 + (d >> 2);
    const int dd   = d & 3;
    float S1 = 0.f, S2 = 0.f;
    #pragma unroll
    for (int qi = 0; qi < 4; ++qi) {
      S1 += s_red[srcb + qi * 64][dd];
      S2 += s_red[srcb + qi * 64][4 + dd];
    }
    float inv = 1.0f / s_sum[sub2][h2];
    float m1 = S1 * inv;
    float va = fmaxf(S2 * inv - m1 * m1, 0.f);
    HQ[(size_t)(bq0 + sub2) * 256 + hd2]  = m1;
    VAR[(size_t)(bq0 + sub2) * 256 + hd2] = va;
  }
}

// ---------------------------------------------------------------------------
// Output projections, K-split: 1024 threads = 128 cols x 8 K-slices.
__global__ __launch_bounds__(1024) void out_proj_ksplit(
    const float* __restrict__ HQ, const float* __restrict__ ow,
    const float* __restrict__ ob, const float* __restrict__ VAR,
    const float* __restrict__ vw, const float* __restrict__ vb,
    float* __restrict__ out)
{
  __shared__ float s_red[8][4][128];
  const int n    = threadIdx.x & 127;
  const int ks   = threadIdx.x >> 7;    // 0..7
  const int r0   = blockIdx.x * 4;
  const int mode = blockIdx.y;
  const float* X    = mode ? VAR : HQ;
  const float* W    = mode ? vw : ow;
  const float* bias = mode ? vb : ob;
  float* Y = out + (size_t)mode * (NB * NQ * OUT_DIM);
  float a0 = 0.f, a1 = 0.f, a2 = 0.f, a3 = 0.f;
  const int k0 = ks * 32;
  #pragma unroll 8
  for (int kk = 0; kk < 32; ++kk) {
    int k = k0 + kk;
    float w = W[k * 128 + n];
    a0 = fmaf(X[(r0 + 0) * 256 + k], w, a0);
    a1 = fmaf(X[(r0 + 1) * 256 + k], w, a1);
    a2 = fmaf(X[(r0 + 2) * 256 + k], w, a2);
    a3 = fmaf(X[(r0 + 3) * 256 + k], w, a3);
  }
  s_red[ks][0][n] = a0; s_red[ks][1][n] = a1;
  s_red[ks][2][n] = a2; s_red[ks][3][n] = a3;
  __syncthreads();
  if (ks == 0) {
    float bb = bias[n];
    #pragma unroll
    for (int i = 0; i < 4; ++i) {
      float v = bb;
      #pragma unroll
      for (int s = 0; s < 8; ++s) v += s_red[s][i][n];
      if (mode) v = softplus_f(v);
      Y[(r0 + i) * 128 + n] = v;
    }
  }
}

// ---------------------------------------------------------------------------
extern "C" void kernel_launch(void* const* d_in, const int* in_sizes, int n_in,
                              void* d_out, int out_size, void* d_ws, size_t ws_size,
                              hipStream_t stream)
{
  const float* h_obs     = (const float*)d_in[0];
  const float* pos_obs   = (const float*)d_in[1];
  const float* pos_query = (const float*)d_in[2];
  const float* fw1       = (const float*)d_in[3];
  const float* fb1       = (const float*)d_in[4];
  const float* fw2       = (const float*)d_in[5];
  const float* fb2       = (const float*)d_in[6];
  const float* log_sigma = (const float*)d_in[7];
  const float* kw1       = (const float*)d_in[8];
  const float* kb1       = (const float*)d_in[9];
  const float* kw2       = (const float*)d_in[10];
  const float* kb2       = (const float*)d_in[11];
  const float* ow        = (const float*)d_in[12];
  const float* ob        = (const float*)d_in[13];
  const float* vw        = (const float*)d_in[14];
  const float* vb        = (const float*)d_in[15];

  float* out = (float*)d_out;
  float* ws  = (float*)d_ws;

  // workspace layout (floats); X1 dead after layer-2 GEMM, reused for HQ
  float* X1  = ws;                 // 262144 (B*NO x 256)
  float* V   = ws + 262144;        // 262144
  float* VAR = ws + 524288;        // 262144
  float* HQ  = X1;

  mlp256_ksplit<1><<<256, 1024, 0, stream>>>(h_obs, fw1, fb1, X1);
  mlp256_ksplit<0><<<256, 1024, 0, stream>>>(X1, fw2, fb2, V);
  attn_fused<<<NB * NQ / 2, 512, 0, stream>>>(V, kw1, kb1, kw2, kb2, log_sigma,
                                              pos_obs, pos_query, HQ, VAR);
  out_proj_ksplit<<<dim3(256, 2), 1024, 0, stream>>>(HQ, ow, ob, VAR, vw, vb, out);
}

// Round 4
// 180.585 us; speedup vs baseline: 1.2620x; 1.0263x over previous
//
#include <hip/hip_runtime.h>
#include <math.h>

#define NB 2
#define NO 512
#define NQ 512
#define LATENT 256
#define NHEADS 8
#define HEAD_DIM 32
#define HD 256
#define OUT_DIM 128
#define LPAD 520   // logits row pitch: float4-aligned, banks spread by 8 per head

typedef float v2f __attribute__((ext_vector_type(2)));

__device__ __forceinline__ v2f splat2(float x) { v2f r; r.x = x; r.y = x; return r; }
__device__ __forceinline__ v2f fma2(v2f a, v2f b, v2f c) { return __builtin_elementwise_fma(a, b, c); }
__device__ __forceinline__ v2f max2(v2f a, v2f b) { return __builtin_elementwise_max(a, b); }

__device__ __forceinline__ float softplus_f(float x) {
  return x > 0.0f ? x + log1pf(expf(-x)) : log1pf(expf(x));
}

// ---------------------------------------------------------------------------
// K-split GEMM: Y(1024x256) = act(X(1024x256) @ W(256x256) + b)
template<int RELU>
__global__ __launch_bounds__(1024) void mlp256_ksplit(
    const float* __restrict__ X, const float* __restrict__ W,
    const float* __restrict__ bias, float* __restrict__ Y)
{
  __shared__ float s_red[4][4][256];
  const int n  = threadIdx.x & 255;
  const int ks = threadIdx.x >> 8;
  const int r0 = blockIdx.x * 4;
  float a0 = 0.f, a1 = 0.f, a2 = 0.f, a3 = 0.f;
  const int k0 = ks * 64;
  #pragma unroll 8
  for (int kk = 0; kk < 64; ++kk) {
    int k = k0 + kk;
    float w = W[k * 256 + n];
    a0 = fmaf(X[(r0 + 0) * 256 + k], w, a0);
    a1 = fmaf(X[(r0 + 1) * 256 + k], w, a1);
    a2 = fmaf(X[(r0 + 2) * 256 + k], w, a2);
    a3 = fmaf(X[(r0 + 3) * 256 + k], w, a3);
  }
  s_red[ks][0][n] = a0; s_red[ks][1][n] = a1;
  s_red[ks][2][n] = a2; s_red[ks][3][n] = a3;
  __syncthreads();
  if (ks == 0) {
    float bb = bias[n];
    #pragma unroll
    for (int i = 0; i < 4; ++i) {
      float v = s_red[0][i][n] + s_red[1][i][n] + s_red[2][i][n] + s_red[3][i][n] + bb;
      if (RELU) v = fmaxf(v, 0.f);
      Y[(r0 + i) * 256 + n] = v;
    }
  }
}

// ---------------------------------------------------------------------------
// Fused attention + output projection. 2 queries per block, 256 threads.
// Phase 1: thread = obs-pair; j-loop shared across both queries; packed-fp32
//          (v_pk_*) accumulation, packing over queries. aq via ds_read_b64.
// Phase 2: softmax, 4 waves x 4 (q,h) combos.
// Phase 3: thread = (q, o-half, h, d4); float4 p + float4 V, pk accumulate.
// Phase 4: reduce -> HQ/VAR in LDS -> fused out_proj epilogue to d_out.
__global__ __launch_bounds__(256, 3) void attn_fused(
    const float* __restrict__ V,         // (B*NO, 256)
    const float* __restrict__ kw1,       // (9, 256)
    const float* __restrict__ kb1,       // (256)
    const float* __restrict__ kw2,       // (256, 8)
    const float* __restrict__ kb2,       // (8)
    const float* __restrict__ log_sigma, // (8)
    const float* __restrict__ pos_obs,   // (B*NO, 3)
    const float* __restrict__ pos_query, // (B*NQ, 3)
    const float* __restrict__ ow,        // (256, 128)
    const float* __restrict__ obias,     // (128)
    const float* __restrict__ vw,        // (256, 128)
    const float* __restrict__ vbias,     // (128)
    float* __restrict__ out)             // mean | var_out, each (B*NQ,128)
{
  __shared__ float2 s_aq2[256];             // per j: {aq_q0, aq_q1}
  __shared__ float  s_logits[2][8 * LPAD];  // 33.3 KB
  __shared__ float  s_red[256][8];          // 8 KB
  __shared__ float  s_hv[2][2][256];        // [q][mean/var][hd], 4 KB
  __shared__ float  s_sum[2][8];
  __shared__ float  s_invs2[8];
  __shared__ float  s_kb2v[8];

  const int t   = threadIdx.x;
  const int bq0 = blockIdx.x * 2;
  const int b   = bq0 >> 9;

  // block-uniform query positions (both queries)
  float pqv[2][3];
  #pragma unroll
  for (int q = 0; q < 2; ++q) {
    pqv[q][0] = pos_query[(bq0 + q) * 3 + 0];
    pqv[q][1] = pos_query[(bq0 + q) * 3 + 1];
    pqv[q][2] = pos_query[(bq0 + q) * 3 + 2];
  }

  // aq for both queries at j = t
  {
    const int j = t;
    float c0 = kw1[0 * 256 + j] + kw1[6 * 256 + j];
    float c1 = kw1[1 * 256 + j] + kw1[7 * 256 + j];
    float c2 = kw1[2 * 256 + j] + kw1[8 * 256 + j];
    float base = kb1[j];
    float a0 = fmaf(pqv[0][0], c0, fmaf(pqv[0][1], c1, fmaf(pqv[0][2], c2, base)));
    float a1 = fmaf(pqv[1][0], c0, fmaf(pqv[1][1], c1, fmaf(pqv[1][2], c2, base)));
    s_aq2[j] = make_float2(a0, a1);
  }
  if (t < 8) {
    float s = expf(log_sigma[t]);
    s_invs2[t] = 1.0f / (s * s + 1e-6f);
    s_kb2v[t]  = kb2[t];
  }
  __syncthreads();

  // this thread's obs pair, positions in registers
  const int o0 = 2 * t, o1 = o0 + 1;
  const float* po = pos_obs + (size_t)b * NO * 3;
  const float p0x = po[o0 * 3 + 0], p0y = po[o0 * 3 + 1], p0z = po[o0 * 3 + 2];
  const float p1x = po[o1 * 3 + 0], p1y = po[o1 * 3 + 1], p1z = po[o1 * 3 + 2];
  v2f pox; pox.x = p0x; pox.y = p1x;
  v2f poy; poy.x = p0y; poy.y = p1y;
  v2f poz; poz.x = p0z; poz.y = p1z;

  float d2v[2][2];
  #pragma unroll
  for (int q = 0; q < 2; ++q) {
    float r0 = pqv[q][0] - p0x, r1 = pqv[q][1] - p0y, r2 = pqv[q][2] - p0z;
    d2v[q][0] = r0 * r0 + r1 * r1 + r2 * r2;
    float s0 = pqv[q][0] - p1x, s1 = pqv[q][1] - p1y, s2 = pqv[q][2] - p1z;
    d2v[q][1] = s0 * s0 + s1 * s1 + s2 * s2;
  }

  // Phase 1: delta accumulation, da[obs][h] packed over queries
  const float* k3 = kw1 + 3 * 256;
  const float* k4 = kw1 + 4 * 256;
  const float* k5 = kw1 + 5 * 256;
  const float* k6 = kw1 + 6 * 256;
  const float* k7 = kw1 + 7 * 256;
  const float* k8 = kw1 + 8 * 256;
  v2f da[2][8];
  #pragma unroll
  for (int h = 0; h < 8; ++h) { da[0][h] = splat2(0.f); da[1][h] = splat2(0.f); }

  #pragma unroll 4
  for (int j = 0; j < 256; ++j) {
    float w0 = k3[j] - k6[j];           // wave-uniform: s_load + VALU
    float w1 = k4[j] - k7[j];
    float w2 = k5[j] - k8[j];
    v2f ao = fma2(pox, splat2(w0), fma2(poy, splat2(w1), poz * splat2(w2)));
    float2 aqp = s_aq2[j];              // one ds_read_b64 broadcast
    v2f aq; aq.x = aqp.x; aq.y = aqp.y;
    v2f h0 = max2(aq + splat2(ao.x), splat2(0.f));  // packed over queries
    v2f h1 = max2(aq + splat2(ao.y), splat2(0.f));
    const float* kr = kw2 + j * 8;      // wave-uniform: s_load_dwordx8
    #pragma unroll
    for (int h = 0; h < 8; ++h) {
      v2f kh = splat2(kr[h]);
      da[0][h] = fma2(h0, kh, da[0][h]);
      da[1][h] = fma2(h1, kh, da[1][h]);
    }
  }

  #pragma unroll
  for (int h = 0; h < 8; ++h) {
    float inv = s_invs2[h];
    float bb  = s_kb2v[h];
    #pragma unroll
    for (int q = 0; q < 2; ++q) {
      float l0 = logf(expf(-d2v[q][0] * inv) + 1e-8f) + da[0][h][q] + bb;
      float l1 = logf(expf(-d2v[q][1] * inv) + 1e-8f) + da[1][h][q] + bb;
      s_logits[q][h * LPAD + o0] = l0;
      s_logits[q][h * LPAD + o1] = l1;
    }
  }
  __syncthreads();

  // Phase 2: softmax over o for each (q,h); 4 waves x 4 combos
  {
    const int wave = t >> 6, lane = t & 63;
    #pragma unroll
    for (int it = 0; it < 4; ++it) {
      const int idx = wave * 4 + it;    // 0..15
      const int q = idx >> 3, h = idx & 7;
      float* pl = &s_logits[q][h * LPAD];
      float l[8];
      float m = -1e30f;
      #pragma unroll
      for (int k = 0; k < 8; ++k) {
        l[k] = pl[k * 64 + lane];
        m = fmaxf(m, l[k]);
      }
      #pragma unroll
      for (int off = 32; off >= 1; off >>= 1) m = fmaxf(m, __shfl_xor(m, off, 64));
      float s = 0.f;
      #pragma unroll
      for (int k = 0; k < 8; ++k) {
        float p = expf(l[k] - m);
        pl[k * 64 + lane] = p;
        s += p;
      }
      #pragma unroll
      for (int off = 32; off >= 1; off >>= 1) s += __shfl_xor(s, off, 64);
      if (lane == 0) s_sum[q][h] = s;
    }
  }
  __syncthreads();

  // Phase 3: thread = (q, o-half, h, d4-group)
  {
    const int q    = t >> 7;
    const int r    = t & 127;
    const int half = r >> 6;
    const int rr   = r & 63;
    const int h    = rr >> 3;
    const int dg   = rr & 7;
    const float* vbase = V + (size_t)b * NO * 256 + (size_t)(half * 256) * 256
                           + h * 32 + dg * 4;
    const float* pl = &s_logits[q][h * LPAD + half * 256];
    v2f s1a = splat2(0.f), s1b = splat2(0.f);
    v2f s2a = splat2(0.f), s2b = splat2(0.f);
    #pragma unroll 2
    for (int oi = 0; oi < 256; oi += 4) {
      float4 pv = *(const float4*)&pl[oi];      // ds_read_b128, conflict-light
      #pragma unroll
      for (int i = 0; i < 4; ++i) {
        float p = (&pv.x)[i];
        float4 vv = *(const float4*)(vbase + (size_t)(oi + i) * 256);
        v2f va;  va.x  = vv.x; va.y  = vv.y;
        v2f vb2; vb2.x = vv.z; vb2.y = vv.w;
        v2f ps = splat2(p);
        s1a = fma2(ps, va,  s1a);
        s1b = fma2(ps, vb2, s1b);
        s2a = fma2(ps * va,  va,  s2a);
        s2b = fma2(ps * vb2, vb2, s2b);
      }
    }
    s_red[t][0] = s1a.x; s_red[t][1] = s1a.y;
    s_red[t][2] = s1b.x; s_red[t][3] = s1b.y;
    s_red[t][4] = s2a.x; s_red[t][5] = s2a.y;
    s_red[t][6] = s2b.x; s_red[t][7] = s2b.y;
  }
  __syncthreads();

  // Reduce o-halves -> mean/var into LDS (t = hd index)
  {
    const int h = t >> 5, d = t & 31, dg = d >> 2, c = d & 3;
    #pragma unroll
    for (int q = 0; q < 2; ++q) {
      const int r0i = q * 128 + h * 8 + dg;
      float S1 = s_red[r0i][c]     + s_red[r0i + 64][c];
      float S2 = s_red[r0i][4 + c] + s_red[r0i + 64][4 + c];
      float inv = 1.0f / s_sum[q][h];
      float m1 = S1 * inv;
      float va = fmaxf(S2 * inv - m1 * m1, 0.f);
      s_hv[q][0][t] = m1;
      s_hv[q][1][t] = va;
    }
  }
  __syncthreads();

  // Phase 4: fused output projection. t = (mode, n); W read once per block-half.
  {
    const int mode = t >> 7;
    const int n    = t & 127;
    const float* W  = mode ? vw : ow;
    const float  bb = mode ? vbias[n] : obias[n];
    float acc0 = bb, acc1 = bb;
    #pragma unroll 4
    for (int k = 0; k < 256; k += 4) {
      float4 x0 = *(const float4*)&s_hv[0][mode][k];
      float4 x1 = *(const float4*)&s_hv[1][mode][k];
      float w0 = W[(k + 0) * 128 + n];
      float w1 = W[(k + 1) * 128 + n];
      float w2 = W[(k + 2) * 128 + n];
      float w3 = W[(k + 3) * 128 + n];
      acc0 = fmaf(x0.x, w0, acc0); acc1 = fmaf(x1.x, w0, acc1);
      acc0 = fmaf(x0.y, w1, acc0); acc1 = fmaf(x1.y, w1, acc1);
      acc0 = fmaf(x0.z, w2, acc0); acc1 = fmaf(x1.z, w2, acc1);
      acc0 = fmaf(x0.w, w3, acc0); acc1 = fmaf(x1.w, w3, acc1);
    }
    if (mode) { acc0 = softplus_f(acc0); acc1 = softplus_f(acc1); }
    float* dst = out + (size_t)mode * (NB * NQ * OUT_DIM);
    dst[(size_t)(bq0 + 0) * OUT_DIM + n] = acc0;
    dst[(size_t)(bq0 + 1) * OUT_DIM + n] = acc1;
  }
}

// ---------------------------------------------------------------------------
extern "C" void kernel_launch(void* const* d_in, const int* in_sizes, int n_in,
                              void* d_out, int out_size, void* d_ws, size_t ws_size,
                              hipStream_t stream)
{
  const float* h_obs     = (const float*)d_in[0];
  const float* pos_obs   = (const float*)d_in[1];
  const float* pos_query = (const float*)d_in[2];
  const float* fw1       = (const float*)d_in[3];
  const float* fb1       = (const float*)d_in[4];
  const float* fw2       = (const float*)d_in[5];
  const float* fb2       = (const float*)d_in[6];
  const float* log_sigma = (const float*)d_in[7];
  const float* kw1       = (const float*)d_in[8];
  const float* kb1       = (const float*)d_in[9];
  const float* kw2       = (const float*)d_in[10];
  const float* kb2       = (const float*)d_in[11];
  const float* ow        = (const float*)d_in[12];
  const float* ob        = (const float*)d_in[13];
  const float* vw        = (const float*)d_in[14];
  const float* vb        = (const float*)d_in[15];

  float* out = (float*)d_out;
  float* ws  = (float*)d_ws;

  float* X1 = ws;                  // (B*NO, 256)
  float* V  = ws + 262144;         // (B*NO, 256)

  mlp256_ksplit<1><<<256, 1024, 0, stream>>>(h_obs, fw1, fb1, X1);
  mlp256_ksplit<0><<<256, 1024, 0, stream>>>(X1, fw2, fb2, V);
  attn_fused<<<NB * NQ / 2, 256, 0, stream>>>(V, kw1, kb1, kw2, kb2, log_sigma,
                                              pos_obs, pos_query,
                                              ow, ob, vw, vb, out);
}